// Round 1
// baseline (351.675 us; speedup 1.0000x reference)
//
#include <hip/hip_runtime.h>

// P2M loss, fused. Sizes fixed by the problem:
//   B=2, M=8192, V={642,2562,10242}, E={1920,7680,30720}
// ws layout: acc (1 float) at +0; knn0 (13446 ints, batch-0 argmin) at +256.

#define DEV __device__ __forceinline__

DEV float blockReduceSum256(float v) {
    #pragma unroll
    for (int o = 32; o > 0; o >>= 1) v += __shfl_down(v, o, 64);
    __shared__ float ws[4];
    int wid = threadIdx.x >> 6;
    if ((threadIdx.x & 63) == 0) ws[wid] = v;
    __syncthreads();
    return (threadIdx.x == 0) ? (ws[0] + ws[1] + ws[2] + ws[3]) : 0.0f;
}

__global__ void kInit(float* acc) {
    if (threadIdx.x == 0) acc[0] = 0.0f;
}

// ---------------- chamfer direction A: per-vertex min over M, + argmin (knn) ----------
// blocks: level0 [0,22), level1 [22,104), level2 [104,426). 256 thr = 64 v-lanes x 4 m-slices.
__global__ __launch_bounds__(256) void kChamferA(
    const float* __restrict__ p0, const float* __restrict__ p1, const float* __restrict__ p2,
    const float* __restrict__ gt, int* __restrict__ knn, float* __restrict__ acc)
{
    const int M = 8192;
    int bid = blockIdx.x;
    int level, V, b, vtile, knnOff;
    const float* pred;
    if (bid < 22)       { level = 0; V = 642;   b = bid / 11;  vtile = bid % 11;  pred = p0; knnOff = 0; }
    else if (bid < 104) { level = 1; V = 2562;  int t = bid - 22;  b = t / 41;  vtile = t % 41;  pred = p1; knnOff = 642; }
    else                { level = 2; V = 10242; int t = bid - 104; b = t / 161; vtile = t % 161; pred = p2; knnOff = 3204; }

    __shared__ float4 sg[1024];
    __shared__ float  redD[256];
    __shared__ int    redI[256];

    int lane  = threadIdx.x & 63;
    int mlane = threadIdx.x >> 6;
    int v = vtile * 64 + lane;
    bool valid = v < V;
    float px = 0.f, py = 0.f, pz = 0.f;
    if (valid) {
        const float* pp = pred + ((size_t)b * V + v) * 3;
        px = pp[0]; py = pp[1]; pz = pp[2];
    }
    float best = 3.0e38f;
    int bi = 0;
    const float* g = gt + (size_t)b * M * 3;

    for (int m0 = 0; m0 < M; m0 += 1024) {
        for (int j = threadIdx.x; j < 1024; j += 256) {
            float gx = g[(m0 + j) * 3 + 0];
            float gy = g[(m0 + j) * 3 + 1];
            float gz = g[(m0 + j) * 3 + 2];
            sg[j] = make_float4(gx, gy, gz, fmaf(gx, gx, fmaf(gy, gy, gz * gz)));
        }
        __syncthreads();
        #pragma unroll 8
        for (int j = mlane; j < 1024; j += 4) {
            float4 q = sg[j];                       // wave-uniform address -> LDS broadcast
            float s = px * q.x;
            s = fmaf(py, q.y, s);
            s = fmaf(pz, q.z, s);
            float d = fmaf(-2.0f, s, q.w);          // |g|^2 - 2 p.g  (|p|^2 added after min)
            if (d < best) { best = d; bi = m0 + j; }
        }
        __syncthreads();
    }

    redD[threadIdx.x] = best;
    redI[threadIdx.x] = bi;
    __syncthreads();

    float contrib = 0.0f;
    if (mlane == 0) {
        #pragma unroll
        for (int k = 1; k < 4; k++) {
            float d2 = redD[lane + (k << 6)];
            int   i2 = redI[lane + (k << 6)];
            if (d2 < best || (d2 == best && i2 < bi)) { best = d2; bi = i2; }
        }
        if (valid) {
            contrib = best + fmaf(px, px, fmaf(py, py, pz * pz));
            if (b == 0) knn[knnOff + v] = bi;       // reference: sel = knn_idx[batch 0][e0]
        }
    }
    if (threadIdx.x < 64) {                          // mlane==0 <=> wave 0
        #pragma unroll
        for (int o = 32; o > 0; o >>= 1) contrib += __shfl_down(contrib, o, 64);
        if (lane == 0) {
            float invBV = (level == 0) ? (1.0f / 1284.0f)
                        : (level == 1) ? (1.0f / 5124.0f)
                                       : (1.0f / 20484.0f);
            atomicAdd(acc, contrib * invBV);
        }
    }
}

// ---------------- chamfer direction B: per-gt-point min over V --------------------------
// blocks: 3 levels x (B=2) x (8192/64=128) = 768. 256 thr = 64 m-lanes x 4 v-slices.
__global__ __launch_bounds__(256) void kChamferB(
    const float* __restrict__ p0, const float* __restrict__ p1, const float* __restrict__ p2,
    const float* __restrict__ gt, float* __restrict__ acc)
{
    const int M = 8192;
    int level = blockIdx.x >> 8;
    int r = blockIdx.x & 255;
    int b = r >> 7;
    int mt = r & 127;
    int V; const float* pred;
    if (level == 0)      { V = 642;   pred = p0; }
    else if (level == 1) { V = 2562;  pred = p1; }
    else                 { V = 10242; pred = p2; }

    __shared__ float4 sp[1024];
    __shared__ float  redD[256];

    int lane  = threadIdx.x & 63;
    int vlane = threadIdx.x >> 6;
    int m = mt * 64 + lane;
    const float* gg = gt + ((size_t)b * M + m) * 3;
    float gx = gg[0], gy = gg[1], gz = gg[2];
    float best = 3.0e38f;
    const float* pb = pred + (size_t)b * V * 3;

    for (int v0 = 0; v0 < V; v0 += 1024) {
        int chunk = min(1024, V - v0);
        for (int j = threadIdx.x; j < chunk; j += 256) {
            float x = pb[(v0 + j) * 3 + 0];
            float y = pb[(v0 + j) * 3 + 1];
            float z = pb[(v0 + j) * 3 + 2];
            sp[j] = make_float4(x, y, z, fmaf(x, x, fmaf(y, y, z * z)));
        }
        __syncthreads();
        #pragma unroll 8
        for (int j = vlane; j < chunk; j += 4) {
            float4 q = sp[j];
            float s = gx * q.x;
            s = fmaf(gy, q.y, s);
            s = fmaf(gz, q.z, s);
            best = fminf(best, fmaf(-2.0f, s, q.w));
        }
        __syncthreads();
    }

    redD[threadIdx.x] = best;
    __syncthreads();
    float contrib = 0.0f;
    if (vlane == 0) {
        best = fminf(fminf(best, redD[lane + 64]), fminf(redD[lane + 128], redD[lane + 192]));
        contrib = best + fmaf(gx, gx, fmaf(gy, gy, gz * gz));
    }
    if (threadIdx.x < 64) {
        #pragma unroll
        for (int o = 32; o > 0; o >>= 1) contrib += __shfl_down(contrib, o, 64);
        if (lane == 0) atomicAdd(acc, contrib * (1.0f / 16384.0f));  // 1/(B*M)
    }
}

// ---------------- edge + normal losses (needs knn from kChamferA) -----------------------
// items: level0 [0,3840), level1 [3840,19200), level2 [19200,80640)   (= B*E per level)
__global__ __launch_bounds__(256) void kEdgeNormal(
    const float* __restrict__ p0, const float* __restrict__ p1, const float* __restrict__ p2,
    const int* __restrict__ e0p, const int* __restrict__ e1p, const int* __restrict__ e2p,
    const float* __restrict__ gtn, const int* __restrict__ knn, float* __restrict__ acc)
{
    const int M = 8192;
    int idx = blockIdx.x * 256 + threadIdx.x;
    float c = 0.0f;
    if (idx < 80640) {
        int E, V, knnOff, t;
        const float* pred; const int* edges;
        if (idx < 3840)       { E = 1920;  V = 642;   knnOff = 0;    pred = p0; edges = e0p; t = idx; }
        else if (idx < 19200) { E = 7680;  V = 2562;  knnOff = 642;  pred = p1; edges = e1p; t = idx - 3840; }
        else                  { E = 30720; V = 10242; knnOff = 3204; pred = p2; edges = e2p; t = idx - 19200; }
        int b = t / E;
        int e = t % E;
        int a0 = edges[e * 2 + 0];
        int a1 = edges[e * 2 + 1];
        const float* P = pred + (size_t)b * V * 3;
        float dx = P[a0 * 3 + 0] - P[a1 * 3 + 0];
        float dy = P[a0 * 3 + 1] - P[a1 * 3 + 1];
        float dz = P[a0 * 3 + 2] - P[a1 * 3 + 2];
        float sq = fmaf(dx, dx, fmaf(dy, dy, dz * dz));
        float inv = 1.0f / fmaxf(sqrtf(sq), 1e-12f);
        int sel = knn[knnOff + a0];
        const float* nr = gtn + ((size_t)b * M + sel) * 3;
        float nx = nr[0], ny = nr[1], nz = nr[2];
        float invn = 1.0f / fmaxf(sqrtf(fmaf(nx, nx, fmaf(ny, ny, nz * nz))), 1e-12f);
        float dotv = fmaf(dx, nx, fmaf(dy, ny, dz * nz)) * inv * invn;
        float iBE = 1.0f / (2.0f * (float)E);
        c = sq * (0.1f * iBE) + fabsf(dotv) * (0.00016f * iBE);
    }
    c = blockReduceSum256(c);
    if (threadIdx.x == 0) atomicAdd(acc, c);
}

// ---------------- laplacian + move losses -----------------------------------------------
// items: level0 [0,1284), level1 [1284,6408), level2 [6408,26892)   (= B*V per level)
__global__ __launch_bounds__(256) void kLapMove(
    const float* __restrict__ p0, const float* __restrict__ p1, const float* __restrict__ p2,
    const float* __restrict__ b0, const float* __restrict__ b1, const float* __restrict__ b2,
    const int* __restrict__ l0p, const int* __restrict__ l1p, const int* __restrict__ l2p,
    float* __restrict__ acc)
{
    int idx = blockIdx.x * 256 + threadIdx.x;
    float c = 0.0f;
    if (idx < 26892) {
        int level, V, t;
        const float *pred, *bef; const int* lap;
        if (idx < 1284)      { level = 0; V = 642;   pred = p0; bef = b0; lap = l0p; t = idx; }
        else if (idx < 6408) { level = 1; V = 2562;  pred = p1; bef = b1; lap = l1p; t = idx - 1284; }
        else                 { level = 2; V = 10242; pred = p2; bef = b2; lap = l2p; t = idx - 6408; }
        int b = t / V;
        int v = t % V;
        const float* P  = pred + ((size_t)b * V + v) * 3;
        const float* Bf = bef  + ((size_t)b * V + v) * 3;
        float dx = Bf[0] - P[0], dy = Bf[1] - P[1], dz = Bf[2] - P[2];
        float sx = 0.f, sy = 0.f, sz = 0.f;
        const int* L = lap + v * 10;
        #pragma unroll
        for (int j = 0; j < 8; j++) {
            int n = L[j];
            if (n >= 0) {
                const float* Pn = pred + ((size_t)b * V + n) * 3;
                const float* Bn = bef  + ((size_t)b * V + n) * 3;
                sx += Bn[0] - Pn[0];
                sy += Bn[1] - Pn[1];
                sz += Bn[2] - Pn[2];
            }
        }
        float invc = 1.0f / (float)L[9];
        float lx = dx - sx * invc, ly = dy - sy * invc, lz = dz - sz * invc;
        float sl = fmaf(lx, lx, fmaf(ly, ly, lz * lz));
        float sm = fmaf(dx, dx, fmaf(dy, dy, dz * dz));
        float lapc = (level == 0) ? 0.2f : 1.0f;
        float iBV = 1.0f / (2.0f * (float)V);
        float scaleLap  = 0.5f * lapc * iBV;                          // W_LAPLACE * LAP_CONST / (B*V)
        float scaleMove = (level > 0) ? (0.1f * lapc * iBV) : 0.0f;   // W_MOVE * LAP_CONST / (B*V), i>0
        c = sl * scaleLap + sm * scaleMove;
    }
    c = blockReduceSum256(c);
    if (threadIdx.x == 0) atomicAdd(acc, c);
}

__global__ void kOut(const float* acc, float* out) {
    if (threadIdx.x == 0) out[0] = acc[0];
}

extern "C" void kernel_launch(void* const* d_in, const int* in_sizes, int n_in,
                              void* d_out, int out_size, void* d_ws, size_t ws_size,
                              hipStream_t stream) {
    const float *gt, *gtn, *pred[3], *bef[3];
    const int *edg[3], *lapx[3];
    if (in_sizes[0] == 49152) {
        // setup_inputs() dict order: gt, gt_normal, then per level: pred, before, edges, lap
        gt  = (const float*)d_in[0];
        gtn = (const float*)d_in[1];
        for (int i = 0; i < 3; i++) {
            pred[i] = (const float*)d_in[2 + 4 * i];
            bef[i]  = (const float*)d_in[3 + 4 * i];
            edg[i]  = (const int*)  d_in[4 + 4 * i];
            lapx[i] = (const int*)  d_in[5 + 4 * i];
        }
    } else {
        // reference signature order fallback
        for (int i = 0; i < 3; i++) pred[i] = (const float*)d_in[i];
        for (int i = 0; i < 3; i++) bef[i]  = (const float*)d_in[3 + i];
        gt  = (const float*)d_in[6];
        gtn = (const float*)d_in[7];
        for (int i = 0; i < 3; i++) lapx[i] = (const int*)d_in[8 + i];
        for (int i = 0; i < 3; i++) edg[i]  = (const int*)d_in[11 + i];
    }

    float* acc = (float*)d_ws;
    int*   knn = (int*)((char*)d_ws + 256);   // 13446 ints: [0,642) L0, [642,3204) L1, [3204,13446) L2

    kInit<<<1, 64, 0, stream>>>(acc);
    kChamferA<<<426, 256, 0, stream>>>(pred[0], pred[1], pred[2], gt, knn, acc);
    kChamferB<<<768, 256, 0, stream>>>(pred[0], pred[1], pred[2], gt, acc);
    kEdgeNormal<<<(80640 + 255) / 256, 256, 0, stream>>>(pred[0], pred[1], pred[2],
                                                         edg[0], edg[1], edg[2], gtn, knn, acc);
    kLapMove<<<(26892 + 255) / 256, 256, 0, stream>>>(pred[0], pred[1], pred[2],
                                                      bef[0], bef[1], bef[2],
                                                      lapx[0], lapx[1], lapx[2], acc);
    kOut<<<1, 64, 0, stream>>>(acc, (float*)d_out);
}

// Round 2
// 244.752 us; speedup vs baseline: 1.4369x; 1.4369x over previous
//
#include <hip/hip_runtime.h>

// P2M loss, fused. B=2, M=8192, V={642,2562,10242}, E={1920,7680,30720}
// ws layout:
//   +0      : float acc (memset 0)
//   +256    : u64 minsA[26892]  packed (ordered_d<<32)|argmin_m, slot = vOff[l]+b*V+v
//   +215424 : u32 minsB[49152]  ordered_d, slot = l*16384+b*8192+m
//   mins regions memset 0xFF (== +max in ordered encoding)

#define DEV __device__ __forceinline__

DEV unsigned int ford(float f) {               // monotone float -> uint
    unsigned int u = __float_as_uint(f);
    return (u & 0x80000000u) ? ~u : (u | 0x80000000u);
}
DEV float funord(unsigned int o) {             // inverse
    unsigned int u = (o & 0x80000000u) ? (o ^ 0x80000000u) : ~o;
    return __uint_as_float(u);
}
DEV unsigned long long umin64(unsigned long long a, unsigned long long b) {
    return a < b ? a : b;
}

DEV float blockReduceSum256(float v) {
    #pragma unroll
    for (int o = 32; o > 0; o >>= 1) v += __shfl_down(v, o, 64);
    __shared__ float ws[4];
    int wid = threadIdx.x >> 6;
    if ((threadIdx.x & 63) == 0) ws[wid] = v;
    __syncthreads();
    return (threadIdx.x == 0) ? (ws[0] + ws[1] + ws[2] + ws[3]) : 0.0f;
}

// ---------------- chamfer A: per-vertex min over M (+argmin), M split in 2 halves ------
// 852 blocks: L0 [0,44), L1 [44,208), L2 [208,852). 256 thr = 64 v-lanes x 4 m-slices.
// Every block: exactly 4096 gt points -> uniform work.
__global__ __launch_bounds__(256) void kChamferA(
    const float* __restrict__ p0, const float* __restrict__ p1, const float* __restrict__ p2,
    const float* __restrict__ gt, unsigned long long* __restrict__ minsA)
{
    int bid = blockIdx.x;
    int V, tiles, vOff, t;
    const float* pred;
    if (bid < 44)       { V = 642;   tiles = 11;  vOff = 0;    pred = p0; t = bid; }
    else if (bid < 208) { V = 2562;  tiles = 41;  vOff = 1284; pred = p1; t = bid - 44; }
    else                { V = 10242; tiles = 161; vOff = 6408; pred = p2; t = bid - 208; }
    int vtile = t % tiles;
    int rest  = t / tiles;
    int b     = rest & 1;
    int mhalf = rest >> 1;

    __shared__ float4 sg[1024];
    __shared__ unsigned long long red[256];

    int lane = threadIdx.x & 63;
    int msl  = threadIdx.x >> 6;          // wave-uniform
    int v = vtile * 64 + lane;
    bool valid = v < V;
    float px = 0.f, py = 0.f, pz = 0.f;
    if (valid) {
        const float* pp = pred + ((size_t)b * V + v) * 3;
        px = pp[0]; py = pp[1]; pz = pp[2];
    }

    float best = 3.0e38f;
    int bi = 0;
    int mbase = mhalf * 4096;
    const float* g = gt + ((size_t)b * 8192 + mbase) * 3;

    for (int c0 = 0; c0 < 4096; c0 += 1024) {
        #pragma unroll
        for (int k = 0; k < 4; k++) {
            int j = threadIdx.x + k * 256;
            const float* gp = g + (size_t)(c0 + j) * 3;
            float gx = gp[0], gy = gp[1], gz = gp[2];
            sg[j] = make_float4(-2.f * gx, -2.f * gy, -2.f * gz,
                                fmaf(gx, gx, fmaf(gy, gy, gz * gz)));
        }
        __syncthreads();
        #pragma unroll 16
        for (int i = 0; i < 256; i++) {
            int j = (i << 2) | msl;       // wave-uniform addr -> LDS broadcast
            float4 q = sg[j];
            float d = fmaf(q.x, px, fmaf(q.y, py, fmaf(q.z, pz, q.w)));
            if (d < best) { best = d; bi = mbase + c0 + j; }
        }
        __syncthreads();
    }

    red[threadIdx.x] = ((unsigned long long)ford(best) << 32) | (unsigned int)bi;
    __syncthreads();
    if (msl == 0 && valid) {
        unsigned long long mm = umin64(umin64(red[lane], red[lane + 64]),
                                       umin64(red[lane + 128], red[lane + 192]));
        atomicMin(&minsA[vOff + b * V + v], mm);
    }
}

// ---------------- chamfer B: per-gt-point min over V, V split into 1024-chunks ---------
// 3840 blocks: L0 [0,256), L1 [256,1024), L2 [1024,3840). 256 thr = 64 m-lanes x 4 v-sl.
__global__ __launch_bounds__(256) void kChamferB(
    const float* __restrict__ p0, const float* __restrict__ p1, const float* __restrict__ p2,
    const float* __restrict__ gt, unsigned int* __restrict__ minsB)
{
    int bid = blockIdx.x;
    int V, lvl, t;
    const float* pred;
    if (bid < 256)       { V = 642;   lvl = 0; pred = p0; t = bid; }
    else if (bid < 1024) { V = 2562;  lvl = 1; pred = p1; t = bid - 256; }
    else                 { V = 10242; lvl = 2; pred = p2; t = bid - 1024; }
    int mtile = t & 127;
    int b     = (t >> 7) & 1;
    int vbase = (t >> 8) * 1024;

    __shared__ float4 sp[1024];
    __shared__ float  red[256];

    #pragma unroll
    for (int k = 0; k < 4; k++) {
        int j = threadIdx.x + k * 256;
        int vi = vbase + j;
        if (vi < V) {
            const float* pp = pred + ((size_t)b * V + vi) * 3;
            float x = pp[0], y = pp[1], z = pp[2];
            sp[j] = make_float4(-2.f * x, -2.f * y, -2.f * z,
                                fmaf(x, x, fmaf(y, y, z * z)));
        } else {
            sp[j] = make_float4(0.f, 0.f, 0.f, 3.0e38f);   // sentinel, never wins
        }
    }
    __syncthreads();

    int lane = threadIdx.x & 63;
    int vsl  = threadIdx.x >> 6;          // wave-uniform
    int m = mtile * 64 + lane;
    const float* gp = gt + ((size_t)b * 8192 + m) * 3;
    float gx = gp[0], gy = gp[1], gz = gp[2];

    float best = 3.0e38f;
    #pragma unroll 8
    for (int i = 0; i < 256; i++) {
        int j = (i << 2) | vsl;
        float4 q = sp[j];
        best = fminf(best, fmaf(q.x, gx, fmaf(q.y, gy, fmaf(q.z, gz, q.w))));
    }

    red[threadIdx.x] = best;
    __syncthreads();
    if (vsl == 0) {
        best = fminf(fminf(red[lane], red[lane + 64]),
                     fminf(red[lane + 128], red[lane + 192]));
        atomicMin(&minsB[lvl * 16384 + b * 8192 + m], ford(best));
    }
}

// ---------------- combine: unpack mins, add own-norm, weighted sum ---------------------
// items: [0,26892) = A slots, [26892,76044) = B slots
__global__ __launch_bounds__(256) void kCombine(
    const unsigned long long* __restrict__ minsA, const unsigned int* __restrict__ minsB,
    const float* __restrict__ p0, const float* __restrict__ p1, const float* __restrict__ p2,
    const float* __restrict__ gt, float* __restrict__ acc)
{
    int idx = blockIdx.x * 256 + threadIdx.x;
    float c = 0.0f;
    if (idx < 26892) {
        int V, base; const float* pred; float inv;
        if (idx < 1284)      { V = 642;   base = 0;    pred = p0; inv = 1.f / 1284.f; }
        else if (idx < 6408) { V = 2562;  base = 1284; pred = p1; inv = 1.f / 5124.f; }
        else                 { V = 10242; base = 6408; pred = p2; inv = 1.f / 20484.f; }
        int t = idx - base;
        int b = t / V;
        int v = t - b * V;
        float d = funord((unsigned int)(minsA[idx] >> 32));
        const float* pp = pred + ((size_t)b * V + v) * 3;
        c = (d + fmaf(pp[0], pp[0], fmaf(pp[1], pp[1], pp[2] * pp[2]))) * inv;
    } else if (idx < 76044) {
        int t = idx - 26892;              // = lvl*16384 + b*8192 + m
        int bm = t & 16383;               // b*8192 + m
        float d = funord(minsB[t]);
        const float* gp = gt + (size_t)bm * 3;
        c = (d + fmaf(gp[0], gp[0], fmaf(gp[1], gp[1], gp[2] * gp[2]))) * (1.f / 16384.f);
    }
    c = blockReduceSum256(c);
    if (threadIdx.x == 0) atomicAdd(acc, c);
}

// ---------------- edge + normal losses (knn = low 32 bits of minsA, b=0 slots) ---------
__global__ __launch_bounds__(256) void kEdgeNormal(
    const float* __restrict__ p0, const float* __restrict__ p1, const float* __restrict__ p2,
    const int* __restrict__ e0p, const int* __restrict__ e1p, const int* __restrict__ e2p,
    const float* __restrict__ gtn, const unsigned long long* __restrict__ minsA,
    float* __restrict__ acc)
{
    int idx = blockIdx.x * 256 + threadIdx.x;
    float c = 0.0f;
    if (idx < 80640) {
        int E, V, vOff, t;
        const float* pred; const int* edges;
        if (idx < 3840)       { E = 1920;  V = 642;   vOff = 0;    pred = p0; edges = e0p; t = idx; }
        else if (idx < 19200) { E = 7680;  V = 2562;  vOff = 1284; pred = p1; edges = e1p; t = idx - 3840; }
        else                  { E = 30720; V = 10242; vOff = 6408; pred = p2; edges = e2p; t = idx - 19200; }
        int b = t / E;
        int e = t % E;
        int a0 = edges[e * 2 + 0];
        int a1 = edges[e * 2 + 1];
        const float* P = pred + (size_t)b * V * 3;
        float dx = P[a0 * 3 + 0] - P[a1 * 3 + 0];
        float dy = P[a0 * 3 + 1] - P[a1 * 3 + 1];
        float dz = P[a0 * 3 + 2] - P[a1 * 3 + 2];
        float sq = fmaf(dx, dx, fmaf(dy, dy, dz * dz));
        float inv = 1.0f / fmaxf(sqrtf(sq), 1e-12f);
        int sel = (int)(unsigned int)(minsA[vOff + a0] & 0xffffffffull);   // b=0 argmin
        const float* nr = gtn + ((size_t)b * 8192 + sel) * 3;
        float nx = nr[0], ny = nr[1], nz = nr[2];
        float invn = 1.0f / fmaxf(sqrtf(fmaf(nx, nx, fmaf(ny, ny, nz * nz))), 1e-12f);
        float dotv = fmaf(dx, nx, fmaf(dy, ny, dz * nz)) * inv * invn;
        float iBE = 1.0f / (2.0f * (float)E);
        c = sq * (0.1f * iBE) + fabsf(dotv) * (0.00016f * iBE);
    }
    c = blockReduceSum256(c);
    if (threadIdx.x == 0) atomicAdd(acc, c);
}

// ---------------- laplacian + move losses ----------------------------------------------
__global__ __launch_bounds__(256) void kLapMove(
    const float* __restrict__ p0, const float* __restrict__ p1, const float* __restrict__ p2,
    const float* __restrict__ b0, const float* __restrict__ b1, const float* __restrict__ b2,
    const int* __restrict__ l0p, const int* __restrict__ l1p, const int* __restrict__ l2p,
    float* __restrict__ acc)
{
    int idx = blockIdx.x * 256 + threadIdx.x;
    float c = 0.0f;
    if (idx < 26892) {
        int level, V, t;
        const float *pred, *bef; const int* lap;
        if (idx < 1284)      { level = 0; V = 642;   pred = p0; bef = b0; lap = l0p; t = idx; }
        else if (idx < 6408) { level = 1; V = 2562;  pred = p1; bef = b1; lap = l1p; t = idx - 1284; }
        else                 { level = 2; V = 10242; pred = p2; bef = b2; lap = l2p; t = idx - 6408; }
        int b = t / V;
        int v = t - b * V;
        const float* P  = pred + ((size_t)b * V + v) * 3;
        const float* Bf = bef  + ((size_t)b * V + v) * 3;
        float dx = Bf[0] - P[0], dy = Bf[1] - P[1], dz = Bf[2] - P[2];
        float sx = 0.f, sy = 0.f, sz = 0.f;
        const int* L = lap + v * 10;
        #pragma unroll
        for (int j = 0; j < 8; j++) {
            int n = L[j];
            if (n >= 0) {
                const float* Pn = pred + ((size_t)b * V + n) * 3;
                const float* Bn = bef  + ((size_t)b * V + n) * 3;
                sx += Bn[0] - Pn[0];
                sy += Bn[1] - Pn[1];
                sz += Bn[2] - Pn[2];
            }
        }
        float invc = 1.0f / (float)L[9];
        float lx = dx - sx * invc, ly = dy - sy * invc, lz = dz - sz * invc;
        float sl = fmaf(lx, lx, fmaf(ly, ly, lz * lz));
        float sm = fmaf(dx, dx, fmaf(dy, dy, dz * dz));
        float lapc = (level == 0) ? 0.2f : 1.0f;
        float iBV = 1.0f / (2.0f * (float)V);
        float scaleLap  = 0.5f * lapc * iBV;
        float scaleMove = (level > 0) ? (0.1f * lapc * iBV) : 0.0f;
        c = sl * scaleLap + sm * scaleMove;
    }
    c = blockReduceSum256(c);
    if (threadIdx.x == 0) atomicAdd(acc, c);
}

__global__ void kOut(const float* acc, float* out) {
    if (threadIdx.x == 0) out[0] = acc[0];
}

extern "C" void kernel_launch(void* const* d_in, const int* in_sizes, int n_in,
                              void* d_out, int out_size, void* d_ws, size_t ws_size,
                              hipStream_t stream) {
    const float *gt, *gtn, *pred[3], *bef[3];
    const int *edg[3], *lapx[3];
    if (in_sizes[0] == 49152) {
        gt  = (const float*)d_in[0];
        gtn = (const float*)d_in[1];
        for (int i = 0; i < 3; i++) {
            pred[i] = (const float*)d_in[2 + 4 * i];
            bef[i]  = (const float*)d_in[3 + 4 * i];
            edg[i]  = (const int*)  d_in[4 + 4 * i];
            lapx[i] = (const int*)  d_in[5 + 4 * i];
        }
    } else {
        for (int i = 0; i < 3; i++) pred[i] = (const float*)d_in[i];
        for (int i = 0; i < 3; i++) bef[i]  = (const float*)d_in[3 + i];
        gt  = (const float*)d_in[6];
        gtn = (const float*)d_in[7];
        for (int i = 0; i < 3; i++) lapx[i] = (const int*)d_in[8 + i];
        for (int i = 0; i < 3; i++) edg[i]  = (const int*)d_in[11 + i];
    }

    float* acc = (float*)d_ws;
    unsigned long long* minsA = (unsigned long long*)((char*)d_ws + 256);      // 26892 u64
    unsigned int*       minsB = (unsigned int*)((char*)d_ws + 215424);         // 49152 u32

    hipMemsetAsync(d_ws, 0, 4, stream);                                        // acc = 0
    hipMemsetAsync((char*)d_ws + 256, 0xFF, 215168 + 196608, stream);          // mins = +max

    kChamferA<<<852, 256, 0, stream>>>(pred[0], pred[1], pred[2], gt, minsA);
    kChamferB<<<3840, 256, 0, stream>>>(pred[0], pred[1], pred[2], gt, minsB);
    kCombine<<<298, 256, 0, stream>>>(minsA, minsB, pred[0], pred[1], pred[2], gt, acc);
    kEdgeNormal<<<315, 256, 0, stream>>>(pred[0], pred[1], pred[2],
                                         edg[0], edg[1], edg[2], gtn, minsA, acc);
    kLapMove<<<106, 256, 0, stream>>>(pred[0], pred[1], pred[2],
                                      bef[0], bef[1], bef[2],
                                      lapx[0], lapx[1], lapx[2], acc);
    kOut<<<1, 64, 0, stream>>>(acc, (float*)d_out);
}

// Round 3
// 140.024 us; speedup vs baseline: 2.5115x; 1.7479x over previous
//
#include <hip/hip_runtime.h>

// P2M loss. B=2, M=8192, V={642,2562,10242}, E={1920,7680,30720}
// 3 launches: kMega (chamfer A+B reg-tiled + lap/move), kCombine, kEdgeOut.
//
// ws layout (bytes):
//   0      : float acc
//   4      : uint  ticket
//   8      : float lapPartials[128]
//   1024   : int   knn[13446]            (level offsets 0/642/3204)
//   54808  : STORE path:  pA0 u64[458752] ; pA1 u32[458752] @3724824 ; pB u32[475136] @5559832  (end 7460376)
//            ATOMIC path: fA0 u64[13446] ; fA1 u32[13446] @162376 ; fB u32[49152] @216160 (end 412768, memset 0xFF)

#define DEV __device__ __forceinline__

DEV unsigned int ford(float f) {
    unsigned int u = __float_as_uint(f);
    return (u & 0x80000000u) ? ~u : (u | 0x80000000u);
}
DEV float funord(unsigned int o) {
    unsigned int u = (o & 0x80000000u) ? (o ^ 0x80000000u) : ~o;
    return __uint_as_float(u);
}
DEV unsigned long long umin64(unsigned long long a, unsigned long long b) { return a < b ? a : b; }

DEV float blockReduceSum256(float v) {
    #pragma unroll
    for (int o = 32; o > 0; o >>= 1) v += __shfl_down(v, o, 64);
    __shared__ float red4[4];
    int wid = threadIdx.x >> 6;
    if ((threadIdx.x & 63) == 0) red4[wid] = v;
    __syncthreads();
    return (threadIdx.x == 0) ? (red4[0] + red4[1] + red4[2] + red4[3]) : 0.0f;
}

// ---------- role A: per-vertex min over a 256-gt chunk, R=14 vertices/lane, 4-wave m-split
template<bool STORE, bool ARGMIN>
DEV void roleA(int a, const float* p0, const float* p1, const float* p2,
               const float* gt, char* ws, char* smem)
{
    const int b = ARGMIN ? 0 : 1;
    int vtG = a >> 5, mc = a & 31;
    int lvl, vtL, V; const float* predL;
    if (vtG == 0)      { lvl = 0; vtL = 0;       V = 642;   predL = p0; }
    else if (vtG < 4)  { lvl = 1; vtL = vtG - 1; V = 2562;  predL = p1; }
    else               { lvl = 2; vtL = vtG - 4; V = 10242; predL = p2; }
    int tid = threadIdx.x, lane = tid & 63, w = tid >> 6;
    float4* SG = (float4*)smem;
    int mbase = mc << 8;
    {   // stage 256 gt points, pre-scaled
        int m = mbase + tid;
        const float* gp = gt + ((size_t)b * 8192 + m) * 3;
        float gx = gp[0], gy = gp[1], gz = gp[2];
        SG[tid] = make_float4(-2.f * gx, -2.f * gy, -2.f * gz, fmaf(gx, gx, fmaf(gy, gy, gz * gz)));
    }
    float px[14], py[14], pz[14];
    #pragma unroll
    for (int r = 0; r < 14; r++) {
        int vr = vtL * 896 + r * 64 + lane;
        int v = vr - (vr >= V ? V : 0);                 // wrap tail (duplicate-safe)
        const float* pp = predL + ((size_t)b * V + v) * 3;
        px[r] = pp[0]; py[r] = pp[1]; pz[r] = pp[2];
    }
    __syncthreads();
    if (ARGMIN) {
        float best[14]; int bi[14];
        #pragma unroll
        for (int r = 0; r < 14; r++) { best[r] = 3.0e38f; bi[r] = 0; }
        #pragma unroll 4
        for (int i = 0; i < 64; i++) {
            int j = (w << 6) + i;
            float4 q = SG[j];                           // wave-uniform -> broadcast
            int cand = mbase + j;
            #pragma unroll
            for (int r = 0; r < 14; r++) {
                float d = fmaf(q.x, px[r], fmaf(q.y, py[r], fmaf(q.z, pz[r], q.w)));
                if (d < best[r]) { best[r] = d; bi[r] = cand; }
            }
        }
        unsigned long long* RED = (unsigned long long*)(smem + 4096);
        #pragma unroll
        for (int r = 0; r < 14; r++)
            RED[w * 896 + r * 64 + lane] = ((unsigned long long)ford(best[r]) << 32) | (unsigned)bi[r];
        __syncthreads();
        for (int s = tid; s < 896; s += 256) {
            unsigned long long mm = umin64(umin64(RED[s], RED[s + 896]),
                                           umin64(RED[s + 1792], RED[s + 2688]));
            if (STORE) {
                ((unsigned long long*)(ws + 54808))[((size_t)(vtG * 896 + s)) * 32 + mc] = mm;
            } else {
                int vr = vtL * 896 + s; int v = vr - (vr >= V ? V : 0);
                int lvlOff = (lvl == 0) ? 0 : (lvl == 1 ? 642 : 3204);
                atomicMin((unsigned long long*)(ws + 54808) + (lvlOff + v), mm);
            }
        }
    } else {
        float best[14];
        #pragma unroll
        for (int r = 0; r < 14; r++) best[r] = 3.0e38f;
        #pragma unroll 2
        for (int i = 0; i < 64; i += 2) {
            int j = (w << 6) + i;
            float4 q0 = SG[j], q1 = SG[j + 1];
            #pragma unroll
            for (int r = 0; r < 14; r++) {
                float d0 = fmaf(q0.x, px[r], fmaf(q0.y, py[r], fmaf(q0.z, pz[r], q0.w)));
                float d1 = fmaf(q1.x, px[r], fmaf(q1.y, py[r], fmaf(q1.z, pz[r], q1.w)));
                best[r] = fminf(fminf(best[r], d0), d1);     // v_min3_f32
            }
        }
        unsigned* RED = (unsigned*)(smem + 4096);
        #pragma unroll
        for (int r = 0; r < 14; r++)
            RED[w * 896 + r * 64 + lane] = ford(best[r]);
        __syncthreads();
        for (int s = tid; s < 896; s += 256) {
            unsigned mm = min(min(RED[s], RED[s + 896]), min(RED[s + 1792], RED[s + 2688]));
            if (STORE) {
                ((unsigned*)(ws + 3724824))[((size_t)(vtG * 896 + s)) * 32 + mc] = mm;
            } else {
                int vr = vtL * 896 + s; int v = vr - (vr >= V ? V : 0);
                int lvlOff = (lvl == 0) ? 0 : (lvl == 1 ? 642 : 3204);
                atomicMin((unsigned*)(ws + 162376) + (lvlOff + v), mm);
            }
        }
    }
}

// ---------- role B: per-gt min over a 512-vertex chunk, R=16 gt/lane, 4-wave v-split
template<bool STORE>
DEV void roleB(int i, const float* p0, const float* p1, const float* p2,
               const float* gt, char* ws, char* smem)
{
    int lvl, V, cc, t, lvlB, baseB;
    if (i < 32)       { lvl = 0; V = 642;   cc = 2;  t = i;       lvlB = 0;     baseB = 0; }
    else if (i < 128) { lvl = 1; V = 2562;  cc = 6;  t = i - 32;  lvlB = 16384; baseB = 32768; }
    else              { lvl = 2; V = 10242; cc = 21; t = i - 128; lvlB = 32768; baseB = 131072; }
    const float* predL = lvl == 0 ? p0 : (lvl == 1 ? p1 : p2);
    int c = t % cc; int rest = t / cc; int mt = rest & 7; int b = rest >> 3;
    int tid = threadIdx.x, lane = tid & 63, w = tid >> 6;
    float4* SP = (float4*)smem;
    int vbase = c * 512;
    #pragma unroll
    for (int k = 0; k < 2; k++) {
        int j = tid + k * 256, v = vbase + j;
        if (v < V) {
            const float* pp = predL + ((size_t)b * V + v) * 3;
            float x = pp[0], y = pp[1], z = pp[2];
            SP[j] = make_float4(-2.f * x, -2.f * y, -2.f * z, fmaf(x, x, fmaf(y, y, z * z)));
        } else SP[j] = make_float4(0.f, 0.f, 0.f, 3.0e38f);   // sentinel
    }
    float gx[16], gy[16], gz[16];
    #pragma unroll
    for (int r = 0; r < 16; r++) {
        int m = mt * 1024 + r * 64 + lane;
        const float* gp = gt + ((size_t)b * 8192 + m) * 3;
        gx[r] = gp[0]; gy[r] = gp[1]; gz[r] = gp[2];
    }
    __syncthreads();
    float best[16];
    #pragma unroll
    for (int r = 0; r < 16; r++) best[r] = 3.0e38f;
    #pragma unroll 2
    for (int i2 = 0; i2 < 128; i2 += 2) {
        int j = (w << 7) + i2;
        float4 q0 = SP[j], q1 = SP[j + 1];
        #pragma unroll
        for (int r = 0; r < 16; r++) {
            float d0 = fmaf(q0.x, gx[r], fmaf(q0.y, gy[r], fmaf(q0.z, gz[r], q0.w)));
            float d1 = fmaf(q1.x, gx[r], fmaf(q1.y, gy[r], fmaf(q1.z, gz[r], q1.w)));
            best[r] = fminf(fminf(best[r], d0), d1);
        }
    }
    unsigned* RED = (unsigned*)(smem + 8192);
    #pragma unroll
    for (int r = 0; r < 16; r++)
        RED[w * 1024 + r * 64 + lane] = ford(best[r]);
    __syncthreads();
    for (int s = tid; s < 1024; s += 256) {
        unsigned mm = min(min(RED[s], RED[s + 1024]), min(RED[s + 2048], RED[s + 3072]));
        int m = mt * 1024 + s;
        if (STORE) ((unsigned*)(ws + 5559832))[baseB + (size_t)((b << 13) + m) * cc + c] = mm;
        else       atomicMin((unsigned*)(ws + 216160) + (lvlB + (b << 13) + m), mm);
    }
}

// ---------- mega: lap [0,128) | B [128,592) | A-b0 [592,1104) | A-b1 [1104,1616)
template<bool STORE>
__global__ __launch_bounds__(256, 3) void kMega(
    const float* __restrict__ p0, const float* __restrict__ p1, const float* __restrict__ p2,
    const float* __restrict__ b0p, const float* __restrict__ b1p, const float* __restrict__ b2p,
    const int* __restrict__ l0, const int* __restrict__ l1, const int* __restrict__ l2,
    const float* __restrict__ gt, char* ws)
{
    extern __shared__ char smem[];
    int bid = blockIdx.x;
    if (bid == 0 && threadIdx.x == 0) { *(float*)ws = 0.f; *(unsigned*)(ws + 4) = 0u; }
    if (bid < 128) {
        float c = 0.0f;
        int idx = bid * 256 + threadIdx.x;
        if (idx < 26892) {
            int level, V, t;
            const float *pred, *bef; const int* lap;
            if (idx < 1284)      { level = 0; V = 642;   pred = p0; bef = b0p; lap = l0; t = idx; }
            else if (idx < 6408) { level = 1; V = 2562;  pred = p1; bef = b1p; lap = l1; t = idx - 1284; }
            else                 { level = 2; V = 10242; pred = p2; bef = b2p; lap = l2; t = idx - 6408; }
            int b = t / V;
            int v = t - b * V;
            const float* P  = pred + ((size_t)b * V + v) * 3;
            const float* Bf = bef  + ((size_t)b * V + v) * 3;
            float dx = Bf[0] - P[0], dy = Bf[1] - P[1], dz = Bf[2] - P[2];
            float sx = 0.f, sy = 0.f, sz = 0.f;
            const int* L = lap + v * 10;
            #pragma unroll
            for (int j = 0; j < 8; j++) {
                int n = L[j];
                if (n >= 0) {
                    const float* Pn = pred + ((size_t)b * V + n) * 3;
                    const float* Bn = bef  + ((size_t)b * V + n) * 3;
                    sx += Bn[0] - Pn[0]; sy += Bn[1] - Pn[1]; sz += Bn[2] - Pn[2];
                }
            }
            float invc = 1.0f / (float)L[9];
            float lx = dx - sx * invc, ly = dy - sy * invc, lz = dz - sz * invc;
            float sl = fmaf(lx, lx, fmaf(ly, ly, lz * lz));
            float sm = fmaf(dx, dx, fmaf(dy, dy, dz * dz));
            float lapc = (level == 0) ? 0.2f : 1.0f;
            float iBV = 1.0f / (2.0f * (float)V);
            c = sl * (0.5f * lapc * iBV) + ((level > 0) ? sm * (0.1f * lapc * iBV) : 0.0f);
        }
        c = blockReduceSum256(c);
        if (threadIdx.x == 0) ((float*)(ws + 8))[bid] = c;
    }
    else if (bid < 592)  roleB<STORE>(bid - 128, p0, p1, p2, gt, ws, smem);
    else if (bid < 1104) roleA<STORE, true >(bid - 592,  p0, p1, p2, gt, ws, smem);
    else                 roleA<STORE, false>(bid - 1104, p0, p1, p2, gt, ws, smem);
}

// ---------- combine: A slots [0,28672), B slots [28672,77824), lap-sum block 304
template<bool STORE>
__global__ __launch_bounds__(256) void kCombine(
    const float* __restrict__ p0, const float* __restrict__ p1, const float* __restrict__ p2,
    const float* __restrict__ gt, char* ws)
{
    int bid = blockIdx.x, tid = threadIdx.x;
    float c = 0.0f;
    if (bid == 304) {
        if (tid < 128) c = ((float*)(ws + 8))[tid];
    } else {
        int idx = bid * 256 + tid;
        if (idx < 28672) {
            int b = idx / 14336;
            int q = idx % 14336;
            int vtG = q / 896, s = q % 896;
            int lvl, vtL, V; const float* predL; int lvlOff; float inv;
            if (vtG == 0)     { lvl = 0; vtL = 0;       V = 642;   predL = p0; lvlOff = 0;    inv = 1.f / 1284.f; }
            else if (vtG < 4) { lvl = 1; vtL = vtG - 1; V = 2562;  predL = p1; lvlOff = 642;  inv = 1.f / 5124.f; }
            else              { lvl = 2; vtL = vtG - 4; V = 10242; predL = p2; lvlOff = 3204; inv = 1.f / 20484.f; }
            int vr = vtL * 896 + s;
            if (vr < V) {                                   // skip wrap duplicates
                float d; unsigned idxm = 0;
                if (STORE) {
                    if (b == 0) {
                        const unsigned long long* P = (const unsigned long long*)(ws + 54808)
                                                      + ((size_t)(vtG * 896 + s)) * 32;
                        unsigned long long mm = ~0ull;
                        #pragma unroll 8
                        for (int k = 0; k < 32; k++) mm = umin64(mm, P[k]);
                        d = funord((unsigned)(mm >> 32)); idxm = (unsigned)mm;
                    } else {
                        const unsigned* P = (const unsigned*)(ws + 3724824)
                                            + ((size_t)(vtG * 896 + s)) * 32;
                        unsigned mm = 0xFFFFFFFFu;
                        #pragma unroll 8
                        for (int k = 0; k < 32; k++) mm = min(mm, P[k]);
                        d = funord(mm);
                    }
                } else {
                    if (b == 0) {
                        unsigned long long mm = ((unsigned long long*)(ws + 54808))[lvlOff + vr];
                        d = funord((unsigned)(mm >> 32)); idxm = (unsigned)mm;
                    } else {
                        d = funord(((unsigned*)(ws + 162376))[lvlOff + vr]);
                    }
                }
                const float* pp = predL + ((size_t)b * V + vr) * 3;
                c = (d + fmaf(pp[0], pp[0], fmaf(pp[1], pp[1], pp[2] * pp[2]))) * inv;
                if (b == 0) ((int*)(ws + 1024))[lvlOff + vr] = (int)idxm;
            }
        } else if (idx < 77824) {
            int jj = idx - 28672;
            int lvl = jj >> 14, r = jj & 16383;            // r = b*8192+m
            int cc = lvl == 0 ? 2 : (lvl == 1 ? 6 : 21);
            int baseB = lvl == 0 ? 0 : (lvl == 1 ? 32768 : 131072);
            float d;
            if (STORE) {
                const unsigned* P = (const unsigned*)(ws + 5559832) + baseB + (size_t)r * cc;
                unsigned mm = 0xFFFFFFFFu;
                for (int k = 0; k < cc; k++) mm = min(mm, P[k]);
                d = funord(mm);
            } else {
                d = funord(((const unsigned*)(ws + 216160))[(lvl << 14) + r]);
            }
            const float* gp = gt + (size_t)r * 3;
            c = (d + fmaf(gp[0], gp[0], fmaf(gp[1], gp[1], gp[2] * gp[2]))) * (1.f / 16384.f);
        }
    }
    c = blockReduceSum256(c);
    if (tid == 0) atomicAdd((float*)ws, c);
}

// ---------- edge + normal + final output (ticket) ----------
__global__ __launch_bounds__(256) void kEdgeOut(
    const float* __restrict__ p0, const float* __restrict__ p1, const float* __restrict__ p2,
    const int* __restrict__ e0p, const int* __restrict__ e1p, const int* __restrict__ e2p,
    const float* __restrict__ gtn, char* ws, float* __restrict__ out)
{
    const int* knn = (const int*)(ws + 1024);
    int idx = blockIdx.x * 256 + threadIdx.x;
    float c = 0.0f;
    {
        int E, V, lvlOff, t;
        const float* pred; const int* edges;
        if (idx < 3840)       { E = 1920;  V = 642;   lvlOff = 0;    pred = p0; edges = e0p; t = idx; }
        else if (idx < 19200) { E = 7680;  V = 2562;  lvlOff = 642;  pred = p1; edges = e1p; t = idx - 3840; }
        else                  { E = 30720; V = 10242; lvlOff = 3204; pred = p2; edges = e2p; t = idx - 19200; }
        int b = t / E;
        int e = t % E;
        int a0 = edges[e * 2 + 0];
        int a1 = edges[e * 2 + 1];
        const float* P = pred + (size_t)b * V * 3;
        float dx = P[a0 * 3 + 0] - P[a1 * 3 + 0];
        float dy = P[a0 * 3 + 1] - P[a1 * 3 + 1];
        float dz = P[a0 * 3 + 2] - P[a1 * 3 + 2];
        float sq = fmaf(dx, dx, fmaf(dy, dy, dz * dz));
        float inv = 1.0f / fmaxf(sqrtf(sq), 1e-12f);
        int sel = knn[lvlOff + a0];                          // b=0 argmin
        const float* nr = gtn + ((size_t)b * 8192 + sel) * 3;
        float nx = nr[0], ny = nr[1], nz = nr[2];
        float invn = 1.0f / fmaxf(sqrtf(fmaf(nx, nx, fmaf(ny, ny, nz * nz))), 1e-12f);
        float dotv = fmaf(dx, nx, fmaf(dy, ny, dz * nz)) * inv * invn;
        float iBE = 1.0f / (2.0f * (float)E);
        c = sq * (0.1f * iBE) + fabsf(dotv) * (0.00016f * iBE);
    }
    c = blockReduceSum256(c);
    if (threadIdx.x == 0) {
        atomicAdd((float*)ws, c);
        __threadfence();
        unsigned t = atomicAdd((unsigned*)(ws + 4), 1u);
        if (t == 314u) out[0] = atomicAdd((float*)ws, 0.0f);
    }
}

extern "C" void kernel_launch(void* const* d_in, const int* in_sizes, int n_in,
                              void* d_out, int out_size, void* d_ws, size_t ws_size,
                              hipStream_t stream) {
    const float *gt, *gtn, *pred[3], *bef[3];
    const int *edg[3], *lapx[3];
    if (in_sizes[0] == 49152) {
        gt  = (const float*)d_in[0];
        gtn = (const float*)d_in[1];
        for (int i = 0; i < 3; i++) {
            pred[i] = (const float*)d_in[2 + 4 * i];
            bef[i]  = (const float*)d_in[3 + 4 * i];
            edg[i]  = (const int*)  d_in[4 + 4 * i];
            lapx[i] = (const int*)  d_in[5 + 4 * i];
        }
    } else {
        for (int i = 0; i < 3; i++) pred[i] = (const float*)d_in[i];
        for (int i = 0; i < 3; i++) bef[i]  = (const float*)d_in[3 + i];
        gt  = (const float*)d_in[6];
        gtn = (const float*)d_in[7];
        for (int i = 0; i < 3; i++) lapx[i] = (const int*)d_in[8 + i];
        for (int i = 0; i < 3; i++) edg[i]  = (const int*)d_in[11 + i];
    }

    char* ws = (char*)d_ws;
    bool store = ws_size >= (size_t)7460376;

    if (store) {
        kMega<true><<<1616, 256, 32768, stream>>>(pred[0], pred[1], pred[2],
                                                  bef[0], bef[1], bef[2],
                                                  lapx[0], lapx[1], lapx[2], gt, ws);
        kCombine<true><<<305, 256, 0, stream>>>(pred[0], pred[1], pred[2], gt, ws);
    } else {
        hipMemsetAsync(ws + 54808, 0xFF, 412768 - 54808, stream);   // final mins = +max
        kMega<false><<<1616, 256, 32768, stream>>>(pred[0], pred[1], pred[2],
                                                   bef[0], bef[1], bef[2],
                                                   lapx[0], lapx[1], lapx[2], gt, ws);
        kCombine<false><<<305, 256, 0, stream>>>(pred[0], pred[1], pred[2], gt, ws);
    }
    kEdgeOut<<<315, 256, 0, stream>>>(pred[0], pred[1], pred[2],
                                      edg[0], edg[1], edg[2], gtn, ws, (float*)d_out);
}